// Round 6
// baseline (361.738 us; speedup 1.0000x reference)
//
#include <hip/hip_runtime.h>
#include <hip/hip_bf16.h>
#include <stdint.h>

// Problem constants
#define FH 37
#define FW 37
#define FC 256
#define NB 4
#define NP 512
#define BNT (NB*NP)        // 2048
#define KDIM (FC*49)       // 12544
#define HID 1024
#define NHEAD 95           // 91 scores + 4 bbox
#define CAP 256            // max compacted active rows (expect ~75)

typedef __bf16 bf16x8 __attribute__((ext_vector_type(8)));
typedef float  f32x4  __attribute__((ext_vector_type(4)));

// ---------------------------------------------------------------------------
// K0: transpose features (b,c,y,x) x4 levels -> ft[(b*4+l)*1369 + yx][c]
// ---------------------------------------------------------------------------
__global__ __launch_bounds__(256) void k_transpose(const float* __restrict__ f0,
                                                   const float* __restrict__ f1,
                                                   const float* __restrict__ f2,
                                                   const float* __restrict__ f3,
                                                   float* __restrict__ ft) {
  __shared__ float tile[32][33];
  int bl = blockIdx.z;             // b*4 + l
  int b = bl >> 2, l = bl & 3;
  const float* src = (l == 0 ? f0 : l == 1 ? f1 : l == 2 ? f2 : f3) + (size_t)b * FC * FH * FW;
  int yx0 = blockIdx.x * 32;
  int c0  = blockIdx.y * 32;
  int tx = threadIdx.x;            // 0..31
  int ty = threadIdx.y;            // 0..7
  #pragma unroll
  for (int i = 0; i < 32; i += 8) {
    int c  = c0 + ty + i;
    int yx = yx0 + tx;
    float v = (yx < FH * FW) ? src[(size_t)c * (FH * FW) + yx] : 0.f;
    tile[ty + i][tx] = v;
  }
  __syncthreads();
  #pragma unroll
  for (int i = 0; i < 32; i += 8) {
    int yx = yx0 + ty + i;
    int c  = c0 + tx;
    if (yx < FH * FW)
      ft[((size_t)bl * (FH * FW) + yx) * FC + c] = tile[tx][ty + i];
  }
}

// ---------------------------------------------------------------------------
// K_compact: active iff sample(0,0) is valid (min sample; monotone in iy/ix).
// ---------------------------------------------------------------------------
__global__ __launch_bounds__(256) void k_compact(const float* __restrict__ props,
                                                 int* __restrict__ count,
                                                 int* __restrict__ list) {
  int bn = blockIdx.x * 256 + threadIdx.x;   // grid 8 -> 2048
  float px1 = props[(size_t)bn * 4 + 0];
  float py1 = props[(size_t)bn * 4 + 1];
  float px2 = props[(size_t)bn * 4 + 2];
  float py2 = props[(size_t)bn * 4 + 3];
  float bw = px2 - px1, bh = py2 - py1;
  float X1 = px1 - 0.5f, Y1 = py1 - 0.5f;
  float binw = bw * (1.f / 7.f), binh = bh * (1.f / 7.f);
  float sy0 = Y1 + ((float)0 * 0.5f + 0.25f) * binh;
  float sx0 = X1 + ((float)0 * 0.5f + 0.25f) * binw;
  bool active = (sy0 <= 37.f) && (sx0 <= 37.f);
  if (active) {
    int s = atomicAdd(count, 1);
    if (s < CAP) list[s] = bn;
  }
}

// ---------------------------------------------------------------------------
// K1: ROI align, one block per ACTIVE row. A layout is W-NATIVE K order:
// k = c*49 + p  (so the GEMM's W read is a sequential stream).
// Full hi/lo row staged in LDS, dumped coalesced as uint4.
// ---------------------------------------------------------------------------
__global__ __launch_bounds__(256) void k_roi(const float* __restrict__ ft,
                                             const float* __restrict__ props,
                                             const int* __restrict__ count,
                                             const int* __restrict__ list,
                                             __hip_bfloat16* __restrict__ Ahi,
                                             __hip_bfloat16* __restrict__ Alo) {
  __shared__ int   s_idx[196][4];
  __shared__ float s_w[196][4];
  __shared__ __align__(16) ushort rowHi[KDIM];
  __shared__ __align__(16) ushort rowLo[KDIM];
  int s = blockIdx.x;
  int cnt = min(*count, CAP);
  if (s >= cnt) return;
  int bn = list[s];
  int b = bn >> 9;
  int t = threadIdx.x;
  if (t < 196) {
    float px1 = props[(size_t)bn * 4 + 0];
    float py1 = props[(size_t)bn * 4 + 1];
    float px2 = props[(size_t)bn * 4 + 2];
    float py2 = props[(size_t)bn * 4 + 3];
    float bw = px2 - px1, bh = py2 - py1;
    float area = bw * bh;
    int lvl = (area >= 1024.f) + (area >= 4096.f) + (area >= 16384.f);
    float X1 = px1 - 0.5f, Y1 = py1 - 0.5f;
    float binw = bw * (1.f / 7.f), binh = bh * (1.f / 7.f);
    int iy = t / 14, ix = t % 14;
    float sy = Y1 + ((float)iy * 0.5f + 0.25f) * binh;
    float sx = X1 + ((float)ix * 0.5f + 0.25f) * binw;
    float valid = (sy >= -1.f && sy <= 37.f && sx >= -1.f && sx <= 37.f) ? 0.25f : 0.f;
    float yc = fminf(fmaxf(sy, 0.f), 36.f);
    float xc = fminf(fmaxf(sx, 0.f), 36.f);
    float y0f = floorf(yc), x0f = floorf(xc);
    int y0 = (int)y0f, x0 = (int)x0f;
    int y1i = min(y0 + 1, 36), x1i = min(x0 + 1, 36);
    float ly = yc - y0f, lx = xc - x0f;
    float hy = 1.f - ly, hx = 1.f - lx;
    int base = ((b * 4 + lvl) * (FH * FW)) * FC;
    s_idx[t][0] = base + (y0 * FW + x0) * FC;
    s_idx[t][1] = base + (y0 * FW + x1i) * FC;
    s_idx[t][2] = base + (y1i * FW + x0) * FC;
    s_idx[t][3] = base + (y1i * FW + x1i) * FC;
    s_w[t][0] = hy * hx * valid;
    s_w[t][1] = hy * lx * valid;
    s_w[t][2] = ly * hx * valid;
    s_w[t][3] = ly * lx * valid;
  }
  __syncthreads();
  int c = t;
  for (int oy = 0; oy < 7; ++oy) {
    for (int ox = 0; ox < 7; ++ox) {
      float acc = 0.f;
      #pragma unroll
      for (int ry = 0; ry < 2; ++ry) {
        #pragma unroll
        for (int rx = 0; rx < 2; ++rx) {
          int sp = (oy * 2 + ry) * 14 + ox * 2 + rx;
          #pragma unroll
          for (int tap = 0; tap < 4; ++tap) {
            float wt = s_w[sp][tap];
            if (wt != 0.f) acc += wt * ft[s_idx[sp][tap] + c];
          }
        }
      }
      int p = oy * 7 + ox;
      __hip_bfloat16 h = __float2bfloat16(acc);
      __hip_bfloat16 l2 = __float2bfloat16(acc - __bfloat162float(h));
      rowHi[c * 49 + p] = *reinterpret_cast<ushort*>(&h);
      rowLo[c * 49 + p] = *reinterpret_cast<ushort*>(&l2);
    }
  }
  __syncthreads();
  const uint4* hs = (const uint4*)rowHi;
  const uint4* ls = (const uint4*)rowLo;
  uint4* hd = (uint4*)(Ahi + (size_t)s * KDIM);
  uint4* ld = (uint4*)(Alo + (size_t)s * KDIM);
  const int NV = KDIM * 2 / 16;     // 1568
  for (int i = t; i < NV; i += 256) { hd[i] = hs[i]; ld[i] = ls[i]; }
}

// ---------------------------------------------------------------------------
// K5 v4: fused split-bf16 GEMM, 128x64 tile, BK=32, 4 waves, static 2-buffer.
// A: bf16 hi/lo [row][K] (lda=Kt), K in W-NATIVE order.
// W: fp32 [k][n] — loadB is a fully sequential stream now.
// part[z][CAP][1024] fp32 partials.  LDS 48KB -> 2 blocks/CU.
// ---------------------------------------------------------------------------
__global__ __launch_bounds__(256, 2) void k_gemm_fused(
    const __hip_bfloat16* __restrict__ Ahi,
    const __hip_bfloat16* __restrict__ Alo,
    const float* __restrict__ Wf,
    float* __restrict__ part,
    const int* __restrict__ countPtr,
    int Kt, int kChunk) {
  int cnt = min(*countPtr, CAP);
  if ((int)blockIdx.x * 128 >= cnt) return;
  __shared__ __align__(16) char lds[49152];  // 2 buf x {Ahi 8K, Alo 8K, Bhi 4K, Blo 4K}
  const int t = threadIdx.x, lane = t & 63, wave = t >> 6;
  const int m0 = blockIdx.x * 128, n0 = blockIdx.y * 64;
  const int kStart = blockIdx.z * kChunk;
  const int niters = kChunk >> 5;            // even

  const int nn = t & 63;                     // B staging: col
  const int q2 = t >> 6;                     // B staging: k-octet 0..3

  const int wm = (wave & 1) * 64, wn2 = (wave >> 1) * 32;
  const int rsel = lane & 15, q = lane >> 4;

  f32x4 acc[4][2];
  #pragma unroll
  for (int m = 0; m < 4; ++m)
    #pragma unroll
    for (int n = 0; n < 2; ++n)
      acc[m][n] = (f32x4){0.f, 0.f, 0.f, 0.f};

  auto loadB = [&](float* v, int k0) {
    const float* p = Wf + (size_t)(k0 + q2 * 8) * HID + n0 + nn;
    #pragma unroll
    for (int j = 0; j < 8; ++j) v[j] = p[(size_t)j * HID];
  };

  auto writeB = [&](int buf, const float* v) {
    bf16x8 hv, lv;
    #pragma unroll
    for (int e = 0; e < 8; ++e) {
      float f = v[e];
      __hip_bfloat16 h = __float2bfloat16(f);
      float fr = f - __bfloat162float(h);
      __hip_bfloat16 l2 = __float2bfloat16(fr);
      hv[e] = *reinterpret_cast<__bf16*>(&h);
      lv[e] = *reinterpret_cast<__bf16*>(&l2);
    }
    char* bh = lds + buf * 24576 + 16384 + nn * 64 + ((q2 ^ (nn & 3)) << 4);
    *(bf16x8*)bh = hv;
    *(bf16x8*)(bh + 4096) = lv;
  };

  auto stageA = [&](int buf, int k0) {
    #pragma unroll
    for (int pl = 0; pl < 2; ++pl) {
      const __hip_bfloat16* src = pl ? Alo : Ahi;
      #pragma unroll
      for (int i = 0; i < 2; ++i) {
        int seg = wave * 2 + i;                  // 0..7 (wave-uniform)
        int row = seg * 16 + (lane >> 2);        // 0..127
        int cq = (lane & 3) ^ (row & 3);         // pre-swizzled source chunk
        const char* g = (const char*)(src + (size_t)(m0 + row) * Kt + k0 + cq * 8);
        char* l = lds + buf * 24576 + pl * 8192 + seg * 1024;
        __builtin_amdgcn_global_load_lds((const unsigned int __attribute__((address_space(1)))*)g,
                                         (unsigned int __attribute__((address_space(3)))*)l,
                                         16, 0, 0);
      }
    }
  };

  auto compute = [&](int buf) {
    const char* base = lds + buf * 24576;
    bf16x8 ah[4], al2[4], bh2[2], bl2[2];
    #pragma unroll
    for (int mf = 0; mf < 4; ++mf) {
      int row = wm + mf * 16 + rsel;
      int off = row * 64 + ((q ^ (row & 3)) << 4);
      ah[mf]  = *(const bf16x8*)(base + off);
      al2[mf] = *(const bf16x8*)(base + 8192 + off);
    }
    #pragma unroll
    for (int nf = 0; nf < 2; ++nf) {
      int col = wn2 + nf * 16 + rsel;
      int off = col * 64 + ((q ^ (col & 3)) << 4);
      bh2[nf] = *(const bf16x8*)(base + 16384 + off);
      bl2[nf] = *(const bf16x8*)(base + 20480 + off);
    }
    #pragma unroll
    for (int mf = 0; mf < 4; ++mf)
      #pragma unroll
      for (int nf = 0; nf < 2; ++nf) {
        acc[mf][nf] = __builtin_amdgcn_mfma_f32_16x16x32_bf16(ah[mf],  bh2[nf], acc[mf][nf], 0, 0, 0);
        acc[mf][nf] = __builtin_amdgcn_mfma_f32_16x16x32_bf16(ah[mf],  bl2[nf], acc[mf][nf], 0, 0, 0);
        acc[mf][nf] = __builtin_amdgcn_mfma_f32_16x16x32_bf16(al2[mf], bh2[nf], acc[mf][nf], 0, 0, 0);
      }
  };

  float vA[8], vB[8];
  // prologue: fill buffer 0
  loadB(vA, kStart);
  stageA(0, kStart);
  writeB(0, vA);
  __syncthreads();

  int k = kStart;
  const int npair = niters >> 1;
  for (int pr = 0; pr < npair; ++pr) {
    loadB(vB, k + 32);
    stageA(1, k + 32);
    compute(0);
    writeB(1, vB);
    __syncthreads();
    bool more = (pr + 1 < npair);
    if (more) {
      loadB(vA, k + 64);
      stageA(0, k + 64);
    }
    compute(1);
    if (more) writeB(0, vA);
    __syncthreads();
    k += 64;
  }

  float* pbase = part + (size_t)blockIdx.z * (CAP * HID);
  #pragma unroll
  for (int mf = 0; mf < 4; ++mf)
    #pragma unroll
    for (int nf = 0; nf < 2; ++nf) {
      int row = m0 + wm + mf * 16 + q * 4;
      int col = n0 + wn2 + nf * 16 + rsel;
      #pragma unroll
      for (int r = 0; r < 4; ++r)
        pbase[(size_t)(row + r) * HID + col] = acc[mf][nf][r];
    }
}

// ---------------------------------------------------------------------------
// K6: reduce FC1 split-K partials + bias + relu -> H1 hi/lo (native k order)
// ---------------------------------------------------------------------------
__global__ __launch_bounds__(256) void k_reduce1(const float* __restrict__ part,
                                                 const float* __restrict__ bias,
                                                 const int* __restrict__ countPtr,
                                                 int S,
                                                 __hip_bfloat16* __restrict__ Hhi,
                                                 __hip_bfloat16* __restrict__ Hlo) {
  int cnt = min(*countPtr, CAP);
  if ((int)(blockIdx.x >> 2) >= cnt) return;   // 4 blocks per row
  size_t i = (size_t)blockIdx.x * 256 + threadIdx.x;
  const size_t tot = (size_t)CAP * HID;
  int col = (int)(i & (HID - 1));
  float a = bias[col];
  for (int s = 0; s < S; ++s) a += part[(size_t)s * tot + i];
  a = fmaxf(a, 0.f);
  __hip_bfloat16 h = __float2bfloat16(a);
  Hhi[i] = h;
  Hlo[i] = __float2bfloat16(a - __bfloat162float(h));
}

// ---------------------------------------------------------------------------
// K_h2c: constant-path hidden2 raw: h2cr[n] += relu(b1[k])*w2[k][n]
// ---------------------------------------------------------------------------
__global__ __launch_bounds__(256) void k_h2c(const float* __restrict__ w2,
                                             const float* __restrict__ b1,
                                             float* __restrict__ h2cr) {
  int n = blockIdx.x * 256 + threadIdx.x;
  int k0 = blockIdx.y * 128;
  float acc = 0.f;
  for (int k = k0; k < k0 + 128; ++k)
    acc += fmaxf(b1[k], 0.f) * w2[(size_t)k * HID + n];
  atomicAdd(&h2cr[n], acc);
}

// ---------------------------------------------------------------------------
// K_outc: outc[j] = bias_j + relu(b2 + h2cr) . col_j(wc|wb)
// ---------------------------------------------------------------------------
__global__ __launch_bounds__(256) void k_outc(const float* __restrict__ h2cr,
                                              const float* __restrict__ b2,
                                              const float* __restrict__ wc,
                                              const float* __restrict__ bc,
                                              const float* __restrict__ wb,
                                              const float* __restrict__ bb,
                                              float* __restrict__ outc) {
  __shared__ float red[4];
  int j = blockIdx.x;           // 0..94
  int t = threadIdx.x;
  float acc = 0.f;
  for (int n = t; n < HID; n += 256) {
    float h = fmaxf(b2[n] + h2cr[n], 0.f);
    float w = (j < 91) ? wc[(size_t)n * 91 + j] : wb[(size_t)n * 4 + (j - 91)];
    acc += h * w;
  }
  #pragma unroll
  for (int o = 32; o; o >>= 1) acc += __shfl_down(acc, o, 64);
  if ((t & 63) == 0) red[t >> 6] = acc;
  __syncthreads();
  if (t == 0) {
    float bj = (j < 91) ? bc[j] : bb[j - 91];
    outc[j] = bj + red[0] + red[1] + red[2] + red[3];
  }
}

// ---------------------------------------------------------------------------
// K_fill: broadcast constant outputs to every row
// ---------------------------------------------------------------------------
__global__ __launch_bounds__(256) void k_fill(const float* __restrict__ outc,
                                              float* __restrict__ out) {
  int i = blockIdx.x * 256 + threadIdx.x;   // grid 760 -> 194560
  const int SC = BNT * 91;
  if (i < SC) out[i] = outc[i % 91];
  else {
    int r = i - SC;
    if (r < BNT * 4) out[SC + r] = outc[91 + (r & 3)];
  }
}

// ---------------------------------------------------------------------------
// K7: fused FC2-reduce + heads for ACTIVE rows (overwrites const fill)
// ---------------------------------------------------------------------------
__global__ __launch_bounds__(256) void k_head(const float* __restrict__ part,
                                              const float* __restrict__ b2,
                                              const float* __restrict__ wc,
                                              const float* __restrict__ bc,
                                              const float* __restrict__ wb,
                                              const float* __restrict__ bb,
                                              const int* __restrict__ count,
                                              const int* __restrict__ list,
                                              float* __restrict__ out) {
  __shared__ float row[HID];
  int s = blockIdx.x;
  int cnt = min(*count, CAP);
  if (s >= cnt) return;
  int bn = list[s];
  int t = threadIdx.x;
  const size_t tot = (size_t)CAP * HID;
  #pragma unroll
  for (int j = 0; j < 4; ++j) {
    int col = t + j * 256;
    float a = b2[col];
    #pragma unroll
    for (int ss = 0; ss < 8; ++ss) a += part[(size_t)ss * tot + (size_t)s * HID + col];
    row[col] = fmaxf(a, 0.f);
  }
  __syncthreads();
  if (t < NHEAD) {
    float acc = (t < 91) ? bc[t] : bb[t - 91];
    if (t < 91) {
      for (int k = 0; k < HID; ++k) acc += row[k] * wc[(size_t)k * 91 + t];
      out[(size_t)bn * 91 + t] = acc;
    } else {
      for (int k = 0; k < HID; ++k) acc += row[k] * wb[(size_t)k * 4 + (t - 91)];
      out[(size_t)BNT * 91 + (size_t)bn * 4 + (t - 91)] = acc;
    }
  }
}

// ---------------------------------------------------------------------------
extern "C" void kernel_launch(void* const* d_in, const int* in_sizes, int n_in,
                              void* d_out, int out_size, void* d_ws, size_t ws_size,
                              hipStream_t stream) {
  const float* f0    = (const float*)d_in[0];
  const float* f1    = (const float*)d_in[1];
  const float* f2    = (const float*)d_in[2];
  const float* f3    = (const float*)d_in[3];
  const float* props = (const float*)d_in[4];
  const float* w1    = (const float*)d_in[5];
  const float* b1    = (const float*)d_in[6];
  const float* w2    = (const float*)d_in[7];
  const float* b2    = (const float*)d_in[8];
  const float* wc    = (const float*)d_in[9];
  const float* bc    = (const float*)d_in[10];
  const float* wb    = (const float*)d_in[11];
  const float* bb    = (const float*)d_in[12];
  float* out = (float*)d_out;

  char* ws = (char*)d_ws;
  size_t off = 0;
  auto alloc = [&](size_t bytes) -> char* {
    char* p = ws + off;
    off += (bytes + 255) & ~(size_t)255;
    return p;
  };
  float*          ft    = (float*)         alloc((size_t)16 * FH * FW * FC * 4);
  __hip_bfloat16* Ahi   = (__hip_bfloat16*)alloc((size_t)CAP * KDIM * 2);
  __hip_bfloat16* Alo   = (__hip_bfloat16*)alloc((size_t)CAP * KDIM * 2);
  float*          part  = (float*)         alloc((size_t)28 * CAP * HID * 4);
  __hip_bfloat16* H1hi  = (__hip_bfloat16*)alloc((size_t)CAP * HID * 2);
  __hip_bfloat16* H1lo  = (__hip_bfloat16*)alloc((size_t)CAP * HID * 2);
  float*          h2cr  = (float*)         alloc(HID * 4);        // \ zeroed by one
  int*            count = (int*)           alloc(256);            // / memset below
  int*            list  = (int*)           alloc(CAP * 4);
  float*          outc  = (float*)         alloc(NHEAD * 4);
  (void)ws_size; (void)in_sizes; (void)n_in; (void)out_size;

  hipMemsetAsync(h2cr, 0, HID * 4 + 256, stream);

  k_transpose<<<dim3(43, 8, 16), dim3(32, 8), 0, stream>>>(f0, f1, f2, f3, ft);
  k_compact<<<8, 256, 0, stream>>>(props, count, list);
  k_roi<<<CAP, 256, 0, stream>>>(ft, props, count, list, Ahi, Alo);

  // Constant path
  k_h2c<<<dim3(4, 8), 256, 0, stream>>>(w2, b1, h2cr);
  k_outc<<<NHEAD, 256, 0, stream>>>(h2cr, b2, wc, bc, wb, bb, outc);
  k_fill<<<760, 256, 0, stream>>>(outc, out);

  // FC1: K=12544 (W-native order), split-K=28 (448/chunk, 14 BK-iters)
  k_gemm_fused<<<dim3(CAP / 128, 16, 28), 256, 0, stream>>>(Ahi, Alo, w1, part, count,
                                                            KDIM, 448);
  k_reduce1<<<CAP * HID / 256, 256, 0, stream>>>(part, b1, count, 28, H1hi, H1lo);
  // FC2: K=1024 native, split-K=8 (128/chunk, 4 BK-iters)
  k_gemm_fused<<<dim3(CAP / 128, 16, 8), 256, 0, stream>>>(H1hi, H1lo, w2, part, count,
                                                           HID, 128);
  // Fused FC2-reduce + heads (overwrites const fill for active rows)
  k_head<<<CAP, 256, 0, stream>>>(part, b2, wc, bc, wb, bb, count, list, out);
}

// Round 7
// 237.081 us; speedup vs baseline: 1.5258x; 1.5258x over previous
//
#include <hip/hip_runtime.h>
#include <hip/hip_bf16.h>
#include <stdint.h>

// Problem constants
#define FH 37
#define FW 37
#define FC 256
#define NB 4
#define NP 512
#define BNT (NB*NP)        // 2048
#define KDIM (FC*49)       // 12544
#define HID 1024
#define NHEAD 95           // 91 scores + 4 bbox
#define CAP 256            // max compacted active rows (expect ~75)

typedef __bf16 bf16x8 __attribute__((ext_vector_type(8)));
typedef float  f32x4  __attribute__((ext_vector_type(4)));

// ---------------------------------------------------------------------------
// K0: transpose features (b,c,y,x) x4 levels -> ft[(b*4+l)*1369 + yx][c]
// ---------------------------------------------------------------------------
__global__ __launch_bounds__(256) void k_transpose(const float* __restrict__ f0,
                                                   const float* __restrict__ f1,
                                                   const float* __restrict__ f2,
                                                   const float* __restrict__ f3,
                                                   float* __restrict__ ft) {
  __shared__ float tile[32][33];
  int bl = blockIdx.z;             // b*4 + l
  int b = bl >> 2, l = bl & 3;
  const float* src = (l == 0 ? f0 : l == 1 ? f1 : l == 2 ? f2 : f3) + (size_t)b * FC * FH * FW;
  int yx0 = blockIdx.x * 32;
  int c0  = blockIdx.y * 32;
  int tx = threadIdx.x;            // 0..31
  int ty = threadIdx.y;            // 0..7
  #pragma unroll
  for (int i = 0; i < 32; i += 8) {
    int c  = c0 + ty + i;
    int yx = yx0 + tx;
    float v = (yx < FH * FW) ? src[(size_t)c * (FH * FW) + yx] : 0.f;
    tile[ty + i][tx] = v;
  }
  __syncthreads();
  #pragma unroll
  for (int i = 0; i < 32; i += 8) {
    int yx = yx0 + ty + i;
    int c  = c0 + tx;
    if (yx < FH * FW)
      ft[((size_t)bl * (FH * FW) + yx) * FC + c] = tile[tx][ty + i];
  }
}

// ---------------------------------------------------------------------------
// K_compact: active iff sample(0,0) is valid (min sample; monotone in iy/ix).
// ---------------------------------------------------------------------------
__global__ __launch_bounds__(256) void k_compact(const float* __restrict__ props,
                                                 int* __restrict__ count,
                                                 int* __restrict__ list) {
  int bn = blockIdx.x * 256 + threadIdx.x;   // grid 8 -> 2048
  float px1 = props[(size_t)bn * 4 + 0];
  float py1 = props[(size_t)bn * 4 + 1];
  float px2 = props[(size_t)bn * 4 + 2];
  float py2 = props[(size_t)bn * 4 + 3];
  float bw = px2 - px1, bh = py2 - py1;
  float X1 = px1 - 0.5f, Y1 = py1 - 0.5f;
  float binw = bw * (1.f / 7.f), binh = bh * (1.f / 7.f);
  float sy0 = Y1 + ((float)0 * 0.5f + 0.25f) * binh;
  float sx0 = X1 + ((float)0 * 0.5f + 0.25f) * binw;
  bool active = (sy0 <= 37.f) && (sx0 <= 37.f);
  if (active) {
    int s = atomicAdd(count, 1);
    if (s < CAP) list[s] = bn;
  }
}

// ---------------------------------------------------------------------------
// K1: ROI align, grid (CAP, 49): block = (active row s, bin p). All-register
// geometry (round-5 proven). Output in W-NATIVE order k = c*49 + p.
// ---------------------------------------------------------------------------
__global__ __launch_bounds__(256) void k_roi(const float* __restrict__ ft,
                                             const float* __restrict__ props,
                                             const int* __restrict__ count,
                                             const int* __restrict__ list,
                                             __hip_bfloat16* __restrict__ Ahi,
                                             __hip_bfloat16* __restrict__ Alo) {
  int s = blockIdx.x;
  int cnt = min(*count, CAP);
  if (s >= cnt) return;
  int bn = list[s];
  int b = bn >> 9;
  int p = blockIdx.y;              // 0..48
  int oy = p / 7, ox = p % 7;
  int c = threadIdx.x;

  float px1 = props[(size_t)bn * 4 + 0];
  float py1 = props[(size_t)bn * 4 + 1];
  float px2 = props[(size_t)bn * 4 + 2];
  float py2 = props[(size_t)bn * 4 + 3];
  float bw = px2 - px1, bh = py2 - py1;
  float area = bw * bh;
  int lvl = (area >= 1024.f) + (area >= 4096.f) + (area >= 16384.f);
  float X1 = px1 - 0.5f, Y1 = py1 - 0.5f;
  float binw = bw * (1.f / 7.f), binh = bh * (1.f / 7.f);
  int fbase = ((b * 4 + lvl) * (FH * FW)) * FC;

  float acc = 0.f;
  #pragma unroll
  for (int ry = 0; ry < 2; ++ry) {
    int iy = oy * 2 + ry;
    float sy = Y1 + ((float)iy * 0.5f + 0.25f) * binh;
    #pragma unroll
    for (int rx = 0; rx < 2; ++rx) {
      int ix = ox * 2 + rx;
      float sx = X1 + ((float)ix * 0.5f + 0.25f) * binw;
      float valid = (sy >= -1.f && sy <= 37.f && sx >= -1.f && sx <= 37.f) ? 0.25f : 0.f;
      float yc = fminf(fmaxf(sy, 0.f), 36.f);
      float xc = fminf(fmaxf(sx, 0.f), 36.f);
      float y0f = floorf(yc), x0f = floorf(xc);
      int y0 = (int)y0f, x0 = (int)x0f;
      int y1i = min(y0 + 1, 36), x1i = min(x0 + 1, 36);
      float ly = yc - y0f, lx = xc - x0f;
      float hy = 1.f - ly, hx = 1.f - lx;
      float w00 = hy * hx * valid, w01 = hy * lx * valid;
      float w10 = ly * hx * valid, w11 = ly * lx * valid;
      if (w00 != 0.f) acc += w00 * ft[fbase + (y0  * FW + x0 ) * FC + c];
      if (w01 != 0.f) acc += w01 * ft[fbase + (y0  * FW + x1i) * FC + c];
      if (w10 != 0.f) acc += w10 * ft[fbase + (y1i * FW + x0 ) * FC + c];
      if (w11 != 0.f) acc += w11 * ft[fbase + (y1i * FW + x1i) * FC + c];
    }
  }
  size_t o = (size_t)s * KDIM + (size_t)c * 49 + p;   // W-native K order
  __hip_bfloat16 h = __float2bfloat16(acc);
  Ahi[o] = h;
  Alo[o] = __float2bfloat16(acc - __bfloat162float(h));
}

// ---------------------------------------------------------------------------
// K5 v5: fused split-bf16 GEMM, 128x128 tile, BK=32, 4 waves, dbuf.
// A: bf16 hi/lo [row][K] (lda=Kt), K in W-native order.
// W: fp32 [k][n] sequential stream; in-kernel fp32->hi/lo conversion.
// 48 MFMA per iteration (~960 cyc cover vs ~900 cyc load latency).
// LDS 64KB -> 2 blocks/CU.  part[z][CAP][1024] fp32 partials.
// ---------------------------------------------------------------------------
__global__ __launch_bounds__(256, 2) void k_gemm_fused(
    const __hip_bfloat16* __restrict__ Ahi,
    const __hip_bfloat16* __restrict__ Alo,
    const float* __restrict__ Wf,
    float* __restrict__ part,
    const int* __restrict__ countPtr,
    int Kt, int kChunk) {
  int cnt = min(*countPtr, CAP);
  if ((int)blockIdx.x * 128 >= cnt) return;
  __shared__ __align__(16) char lds[65536];  // 2 buf x {Ahi 8K, Alo 8K, Bhi 8K, Blo 8K}
  const int t = threadIdx.x, lane = t & 63, wave = t >> 6;
  const int m0 = blockIdx.x * 128, n0 = blockIdx.y * 128;
  const int kStart = blockIdx.z * kChunk;
  const int niters = kChunk >> 5;            // even

  const int nn = t & 127;                    // B staging: col 0..127
  const int kq = t >> 7;                     // B staging: k-half 0/1 (16 k each)

  const int wm = (wave >> 1) * 64, wn = (wave & 1) * 64;
  const int rsel = lane & 15, q = lane >> 4;

  f32x4 acc[4][4];
  #pragma unroll
  for (int m = 0; m < 4; ++m)
    #pragma unroll
    for (int n = 0; n < 4; ++n)
      acc[m][n] = (f32x4){0.f, 0.f, 0.f, 0.f};

  auto loadB = [&](float* v, int k0) {
    const float* p = Wf + (size_t)(k0 + kq * 16) * HID + n0 + nn;
    #pragma unroll
    for (int j = 0; j < 16; ++j) v[j] = p[(size_t)j * HID];
  };

  auto writeB = [&](int buf, const float* v) {
    char* bh = lds + buf * 32768 + 16384;
    char* bl = lds + buf * 32768 + 24576;
    #pragma unroll
    for (int hh = 0; hh < 2; ++hh) {         // k-octet kq*2+hh
      bf16x8 hv, lv;
      #pragma unroll
      for (int e = 0; e < 8; ++e) {
        float f = v[hh * 8 + e];
        __hip_bfloat16 h = __float2bfloat16(f);
        float fr = f - __bfloat162float(h);
        __hip_bfloat16 l2 = __float2bfloat16(fr);
        hv[e] = *reinterpret_cast<__bf16*>(&h);
        lv[e] = *reinterpret_cast<__bf16*>(&l2);
      }
      int oct = kq * 2 + hh;
      int off = nn * 64 + ((oct ^ (nn & 3)) << 4);
      *(bf16x8*)(bh + off) = hv;
      *(bf16x8*)(bl + off) = lv;
    }
  };

  auto stageA = [&](int buf, int k0) {
    #pragma unroll
    for (int pl = 0; pl < 2; ++pl) {
      const __hip_bfloat16* src = pl ? Alo : Ahi;
      #pragma unroll
      for (int i = 0; i < 2; ++i) {
        int seg = wave * 2 + i;                  // 0..7 (wave-uniform)
        int row = seg * 16 + (lane >> 2);        // 0..127
        int cq = (lane & 3) ^ (row & 3);         // pre-swizzled source chunk
        const char* g = (const char*)(src + (size_t)(m0 + row) * Kt + k0 + cq * 8);
        char* l = lds + buf * 32768 + pl * 8192 + seg * 1024;
        __builtin_amdgcn_global_load_lds((const unsigned int __attribute__((address_space(1)))*)g,
                                         (unsigned int __attribute__((address_space(3)))*)l,
                                         16, 0, 0);
      }
    }
  };

  auto compute = [&](int buf) {
    const char* base = lds + buf * 32768;
    bf16x8 ah[4], al2[4], bh2[4], bl2[4];
    #pragma unroll
    for (int mf = 0; mf < 4; ++mf) {
      int row = wm + mf * 16 + rsel;
      int off = row * 64 + ((q ^ (row & 3)) << 4);
      ah[mf]  = *(const bf16x8*)(base + off);
      al2[mf] = *(const bf16x8*)(base + 8192 + off);
    }
    #pragma unroll
    for (int nf = 0; nf < 4; ++nf) {
      int col = wn + nf * 16 + rsel;
      int off = col * 64 + ((q ^ (col & 3)) << 4);
      bh2[nf] = *(const bf16x8*)(base + 16384 + off);
      bl2[nf] = *(const bf16x8*)(base + 24576 + off);
    }
    #pragma unroll
    for (int mf = 0; mf < 4; ++mf)
      #pragma unroll
      for (int nf = 0; nf < 4; ++nf) {
        acc[mf][nf] = __builtin_amdgcn_mfma_f32_16x16x32_bf16(ah[mf],  bh2[nf], acc[mf][nf], 0, 0, 0);
        acc[mf][nf] = __builtin_amdgcn_mfma_f32_16x16x32_bf16(ah[mf],  bl2[nf], acc[mf][nf], 0, 0, 0);
        acc[mf][nf] = __builtin_amdgcn_mfma_f32_16x16x32_bf16(al2[mf], bh2[nf], acc[mf][nf], 0, 0, 0);
      }
  };

  float vA[16], vB[16];
  // prologue: fill buffer 0
  loadB(vA, kStart);
  stageA(0, kStart);
  writeB(0, vA);
  __syncthreads();

  int k = kStart;
  const int npair = niters >> 1;
  for (int pr = 0; pr < npair; ++pr) {
    loadB(vB, k + 32);
    stageA(1, k + 32);
    compute(0);
    writeB(1, vB);
    __syncthreads();
    bool more = (pr + 1 < npair);
    if (more) {
      loadB(vA, k + 64);
      stageA(0, k + 64);
    }
    compute(1);
    if (more) writeB(0, vA);
    __syncthreads();
    k += 64;
  }

  float* pbase = part + (size_t)blockIdx.z * (CAP * HID);
  #pragma unroll
  for (int mf = 0; mf < 4; ++mf)
    #pragma unroll
    for (int nf = 0; nf < 4; ++nf) {
      int row = m0 + wm + mf * 16 + q * 4;
      int col = n0 + wn + nf * 16 + rsel;
      #pragma unroll
      for (int r = 0; r < 4; ++r)
        pbase[(size_t)(row + r) * HID + col] = acc[mf][nf][r];
    }
}

// ---------------------------------------------------------------------------
// K6: reduce FC1 split-K partials + bias + relu -> H1 hi/lo
// ---------------------------------------------------------------------------
__global__ __launch_bounds__(256) void k_reduce1(const float* __restrict__ part,
                                                 const float* __restrict__ bias,
                                                 const int* __restrict__ countPtr,
                                                 int S,
                                                 __hip_bfloat16* __restrict__ Hhi,
                                                 __hip_bfloat16* __restrict__ Hlo) {
  int cnt = min(*countPtr, CAP);
  if ((int)(blockIdx.x >> 2) >= cnt) return;   // 4 blocks per row
  size_t i = (size_t)blockIdx.x * 256 + threadIdx.x;
  const size_t tot = (size_t)CAP * HID;
  int col = (int)(i & (HID - 1));
  float a = bias[col];
  for (int s = 0; s < S; ++s) a += part[(size_t)s * tot + i];
  a = fmaxf(a, 0.f);
  __hip_bfloat16 h = __float2bfloat16(a);
  Hhi[i] = h;
  Hlo[i] = __float2bfloat16(a - __bfloat162float(h));
}

// ---------------------------------------------------------------------------
// K_h2c: constant-path hidden2 raw: h2cr[n] += relu(b1[k])*w2[k][n]
// ---------------------------------------------------------------------------
__global__ __launch_bounds__(256) void k_h2c(const float* __restrict__ w2,
                                             const float* __restrict__ b1,
                                             float* __restrict__ h2cr) {
  int n = blockIdx.x * 256 + threadIdx.x;
  int k0 = blockIdx.y * 128;
  float acc = 0.f;
  for (int k = k0; k < k0 + 128; ++k)
    acc += fmaxf(b1[k], 0.f) * w2[(size_t)k * HID + n];
  atomicAdd(&h2cr[n], acc);
}

// ---------------------------------------------------------------------------
// K_outc: outc[j] = bias_j + relu(b2 + h2cr) . col_j(wc|wb)
// ---------------------------------------------------------------------------
__global__ __launch_bounds__(256) void k_outc(const float* __restrict__ h2cr,
                                              const float* __restrict__ b2,
                                              const float* __restrict__ wc,
                                              const float* __restrict__ bc,
                                              const float* __restrict__ wb,
                                              const float* __restrict__ bb,
                                              float* __restrict__ outc) {
  __shared__ float red[4];
  int j = blockIdx.x;           // 0..94
  int t = threadIdx.x;
  float acc = 0.f;
  for (int n = t; n < HID; n += 256) {
    float h = fmaxf(b2[n] + h2cr[n], 0.f);
    float w = (j < 91) ? wc[(size_t)n * 91 + j] : wb[(size_t)n * 4 + (j - 91)];
    acc += h * w;
  }
  #pragma unroll
  for (int o = 32; o; o >>= 1) acc += __shfl_down(acc, o, 64);
  if ((t & 63) == 0) red[t >> 6] = acc;
  __syncthreads();
  if (t == 0) {
    float bj = (j < 91) ? bc[j] : bb[j - 91];
    outc[j] = bj + red[0] + red[1] + red[2] + red[3];
  }
}

// ---------------------------------------------------------------------------
// K_fill: broadcast constant outputs to every row
// ---------------------------------------------------------------------------
__global__ __launch_bounds__(256) void k_fill(const float* __restrict__ outc,
                                              float* __restrict__ out) {
  int i = blockIdx.x * 256 + threadIdx.x;   // grid 760 -> 194560
  const int SC = BNT * 91;
  if (i < SC) out[i] = outc[i % 91];
  else {
    int r = i - SC;
    if (r < BNT * 4) out[SC + r] = outc[91 + (r & 3)];
  }
}

// ---------------------------------------------------------------------------
// K7: fused FC2-reduce + heads for ACTIVE rows (overwrites const fill)
// ---------------------------------------------------------------------------
__global__ __launch_bounds__(256) void k_head(const float* __restrict__ part,
                                              const float* __restrict__ b2,
                                              const float* __restrict__ wc,
                                              const float* __restrict__ bc,
                                              const float* __restrict__ wb,
                                              const float* __restrict__ bb,
                                              const int* __restrict__ count,
                                              const int* __restrict__ list,
                                              float* __restrict__ out) {
  __shared__ float row[HID];
  int s = blockIdx.x;
  int cnt = min(*count, CAP);
  if (s >= cnt) return;
  int bn = list[s];
  int t = threadIdx.x;
  const size_t tot = (size_t)CAP * HID;
  #pragma unroll
  for (int j = 0; j < 4; ++j) {
    int col = t + j * 256;
    float a = b2[col];
    #pragma unroll
    for (int ss = 0; ss < 8; ++ss) a += part[(size_t)ss * tot + (size_t)s * HID + col];
    row[col] = fmaxf(a, 0.f);
  }
  __syncthreads();
  if (t < NHEAD) {
    float acc = (t < 91) ? bc[t] : bb[t - 91];
    if (t < 91) {
      for (int k = 0; k < HID; ++k) acc += row[k] * wc[(size_t)k * 91 + t];
      out[(size_t)bn * 91 + t] = acc;
    } else {
      for (int k = 0; k < HID; ++k) acc += row[k] * wb[(size_t)k * 4 + (t - 91)];
      out[(size_t)BNT * 91 + (size_t)bn * 4 + (t - 91)] = acc;
    }
  }
}

// ---------------------------------------------------------------------------
extern "C" void kernel_launch(void* const* d_in, const int* in_sizes, int n_in,
                              void* d_out, int out_size, void* d_ws, size_t ws_size,
                              hipStream_t stream) {
  const float* f0    = (const float*)d_in[0];
  const float* f1    = (const float*)d_in[1];
  const float* f2    = (const float*)d_in[2];
  const float* f3    = (const float*)d_in[3];
  const float* props = (const float*)d_in[4];
  const float* w1    = (const float*)d_in[5];
  const float* b1    = (const float*)d_in[6];
  const float* w2    = (const float*)d_in[7];
  const float* b2    = (const float*)d_in[8];
  const float* wc    = (const float*)d_in[9];
  const float* bc    = (const float*)d_in[10];
  const float* wb    = (const float*)d_in[11];
  const float* bb    = (const float*)d_in[12];
  float* out = (float*)d_out;

  char* ws = (char*)d_ws;
  size_t off = 0;
  auto alloc = [&](size_t bytes) -> char* {
    char* p = ws + off;
    off += (bytes + 255) & ~(size_t)255;
    return p;
  };
  float*          ft    = (float*)         alloc((size_t)16 * FH * FW * FC * 4);
  __hip_bfloat16* Ahi   = (__hip_bfloat16*)alloc((size_t)CAP * KDIM * 2);
  __hip_bfloat16* Alo   = (__hip_bfloat16*)alloc((size_t)CAP * KDIM * 2);
  float*          part  = (float*)         alloc((size_t)28 * CAP * HID * 4);
  __hip_bfloat16* H1hi  = (__hip_bfloat16*)alloc((size_t)CAP * HID * 2);
  __hip_bfloat16* H1lo  = (__hip_bfloat16*)alloc((size_t)CAP * HID * 2);
  float*          h2cr  = (float*)         alloc(HID * 4);        // \ zeroed by one
  int*            count = (int*)           alloc(256);            // / memset below
  int*            list  = (int*)           alloc(CAP * 4);
  float*          outc  = (float*)         alloc(NHEAD * 4);
  (void)ws_size; (void)in_sizes; (void)n_in; (void)out_size;

  hipMemsetAsync(h2cr, 0, HID * 4 + 256, stream);

  k_transpose<<<dim3(43, 8, 16), dim3(32, 8), 0, stream>>>(f0, f1, f2, f3, ft);
  k_compact<<<8, 256, 0, stream>>>(props, count, list);
  k_roi<<<dim3(CAP, 49), 256, 0, stream>>>(ft, props, count, list, Ahi, Alo);

  // Constant path
  k_h2c<<<dim3(4, 8), 256, 0, stream>>>(w2, b1, h2cr);
  k_outc<<<NHEAD, 256, 0, stream>>>(h2cr, b2, wc, bc, wb, bb, outc);
  k_fill<<<760, 256, 0, stream>>>(outc, out);

  // FC1: K=12544 (W-native order), split-K=28 (448/chunk, 14 BK-iters)
  k_gemm_fused<<<dim3(CAP / 128, 8, 28), 256, 0, stream>>>(Ahi, Alo, w1, part, count,
                                                           KDIM, 448);
  k_reduce1<<<CAP * HID / 256, 256, 0, stream>>>(part, b1, count, 28, H1hi, H1lo);
  // FC2: K=1024 native, split-K=8 (128/chunk, 4 BK-iters)
  k_gemm_fused<<<dim3(CAP / 128, 8, 8), 256, 0, stream>>>(H1hi, H1lo, w2, part, count,
                                                          HID, 128);
  // Fused FC2-reduce + heads (overwrites const fill for active rows)
  k_head<<<CAP, 256, 0, stream>>>(part, b2, wc, bc, wb, bb, count, list, out);
}